// Round 11
// baseline (37.600 us; speedup 1.0000x reference)
//
#include <hip/hip_runtime.h>
#include <stdint.h>

#define NE    7
#define DD    64
#define NDC   3
#define BLOCK 256
#define ROWS  128       // rows per block; B = 2048 * 128 exactly
#define NFRAG 18        // W^T A-fragments: 8 (L1) + 8 (L2) + 2 (L3)

typedef __fp16   half8 __attribute__((ext_vector_type(8)));
typedef float    f32x4 __attribute__((ext_vector_type(4)));
typedef uint32_t u32x4 __attribute__((ext_vector_type(4)));
typedef __fp16   h2_t  __attribute__((ext_vector_type(2)));

typedef const void __attribute__((address_space(1))) gvoid_t;
typedef void       __attribute__((address_space(3))) lvoid_t;

__device__ __forceinline__ uint32_t pkrtz(float a, float b) {
  h2_t h = __builtin_amdgcn_cvt_pkrtz(a, b);
  return __builtin_bit_cast(uint32_t, h);
}

__device__ __forceinline__ f32x4 mfma16(u32x4 a, u32x4 b, f32x4 c) {
  return __builtin_amdgcn_mfma_f32_16x16x32_f16(
      __builtin_bit_cast(half8, a), __builtin_bit_cast(half8, b), c, 0, 0, 0);
}

__device__ __forceinline__ u32x4 relu_pack(f32x4 lo, f32x4 hi) {
  u32x4 t = { pkrtz(fmaxf(lo[0],0.f), fmaxf(lo[1],0.f)),
              pkrtz(fmaxf(lo[2],0.f), fmaxf(lo[3],0.f)),
              pkrtz(fmaxf(hi[0],0.f), fmaxf(hi[1],0.f)),
              pkrtz(fmaxf(hi[2],0.f), fmaxf(hi[3],0.f)) };
  return t;
}

// ---- pack W^T into A-fragment layout (HW-verified R4) ----
// lane l: row n = 16*nt + (l&15); dword d, half h: kk = 16*(d>>1)+4*(l>>4)+2*(d&1)+h;
// k = 32*ks + kk; value = W[k][n]  (W row-major [k][n]).
__global__ __launch_bounds__(BLOCK) void pack_w(
    const float* __restrict__ W1, const float* __restrict__ W2,
    const float* __restrict__ W3, uint32_t* __restrict__ ws) {
  const int e = blockIdx.x;
  const float* Wl0 = W1 + e*DD*DD;
  const float* Wl1 = W2 + e*DD*DD;
  const float* Wl2 = W3 + e*DD*NDC;
  for (int idx = threadIdx.x; idx < NFRAG*64; idx += BLOCK) {
    const int f = idx >> 6, l = idx & 63;
    int layer, fl;
    if (f < 8)       { layer = 0; fl = f; }
    else if (f < 16) { layer = 1; fl = f - 8; }
    else             { layer = 2; fl = f - 16; }
    const int nt = (layer < 2) ? (fl >> 1) : 0;
    const int ks = fl & 1;
    const int n  = nt*16 + (l & 15);
    const int g  = l >> 4;
    uint32_t dst[4];
    for (int d = 0; d < 4; ++d) {
      float v[2];
      for (int h = 0; h < 2; ++h) {
        const int kk = 16*(d>>1) + 4*g + 2*(d&1) + h;
        const int k  = 32*ks + kk;
        float val;
        if (layer == 0)      val = Wl0[k*DD + n];
        else if (layer == 1) val = Wl1[k*DD + n];
        else                 val = (n < NDC) ? Wl2[k*NDC + n] : 0.0f;
        v[h] = val;
      }
      dst[d] = pkrtz(v[0], v[1]);
    }
    uint32_t* p = ws + ((size_t)(e*NFRAG + f)*64 + l)*4;
    p[0]=dst[0]; p[1]=dst[1]; p[2]=dst[2]; p[3]=dst[3];
  }
}

// ---- fused: global_load_lds X stream -> LDS sort -> grouped MFMA ----
__global__ __launch_bounds__(BLOCK, 3) void fused(
    const float* __restrict__ X, const int* __restrict__ S,
    const u32x4* __restrict__ wf,
    const float* __restrict__ b1, const float* __restrict__ b2,
    const float* __restrict__ b3,
    float* __restrict__ out, int B)
{
  __shared__ __align__(16) float pk[ROWS*DD];   // 32 KB fp32 X, slot-swizzled via source
  __shared__ uint16_t srt[ROWS];
  __shared__ int wcnt[2][NE];
  __shared__ int woff[2][NE];
  __shared__ int cnt[NE];

  const int tid  = threadIdx.x;
  const int wv   = tid >> 6, lane = tid & 63;
  const int r15  = lane & 15, g = lane >> 4;
  const int base = blockIdx.x * ROWS;

  // ---- A1: route ballots (waves 0-1 own rows; 64 rows per wave) ----
  int e_i = 0, myprefix = 0;
  if (wv < 2) {
    e_i = S[base + tid];
    unsigned long long mk[NE];
    #pragma unroll
    for (int e = 0; e < NE; ++e) mk[e] = __ballot(e_i == e);
    #pragma unroll
    for (int e = 0; e < NE; ++e)
      if (e_i == e) myprefix = __popcll(mk[e] & ((1ull << lane) - 1ull));
    if (lane < NE) wcnt[wv][lane] = __popcll(mk[lane]);
  }

  // ---- B: stream X -> LDS via global_load_lds (fire-and-forget, 8 instrs/wave) ----
  // wave wv covers rows [wv*32, wv*32+32); instr i covers 4 rows (1 KB).
  // lane l -> row = wv*32 + i*4 + (l>>4), physical slot p = l&15 holds logical
  // slot p ^ (row&7)  (involution; read side applies the same XOR).
  {
    const float* Xb = X + (size_t)base * DD;
    #pragma unroll
    for (int i = 0; i < 8; ++i) {
      const int row  = wv*32 + i*4 + (lane >> 4);
      const int slot = (lane & 15) ^ (row & 7);
      const float* src = Xb + row*DD + slot*4;
      lvoid_t* dst = (lvoid_t*)(pk + (wv*32 + i*4)*DD);
      __builtin_amdgcn_global_load_lds((gvoid_t*)src, dst, 16, 0, 0);
    }
  }
  __syncthreads();   // wcnt visible

  // ---- A2: serial 14-scan ----
  if (tid == 0) {
    int acc = 0;
    for (int e = 0; e < NE; ++e) {
      const int s0 = acc;
      for (int w = 0; w < 2; ++w) { woff[w][e] = acc; acc += wcnt[w][e]; }
      cnt[e] = acc - s0;
    }
  }
  __syncthreads();

  // ---- A3: scatter sorted list ----
  if (tid < ROWS) srt[woff[wv][e_i] + myprefix] = (uint16_t)tid;
  asm volatile("s_waitcnt vmcnt(0)" ::: "memory");
  __builtin_amdgcn_sched_barrier(0);
  __syncthreads();

  // ---- C: grouped MFMA passes (waves round-robin) ----
  int pst[NE + 1];
  {
    int tp = 0;
    #pragma unroll
    for (int e = 0; e < NE; ++e) { pst[e] = tp; tp += (cnt[e] + 31) >> 5; }
    pst[NE] = tp;
  }

  for (int p = wv; p < pst[NE]; p += 4) {
    int e = 0;
    #pragma unroll
    for (int q2 = 1; q2 < NE; ++q2) if (p >= pst[q2]) e = q2;
    const int ch    = p - pst[e];
    const int m     = min(32, cnt[e] - ch*32);
    const int sbase = woff[0][e] + ch*32;

    // A-fragments: 18 fat 1-KB L2-hot loads, issued first
    const u32x4* wse = wf + (size_t)e*NFRAG*64;
    u32x4 af[NFRAG];
    #pragma unroll
    for (int f = 0; f < NFRAG; ++f) af[f] = wse[f*64 + lane];

    #pragma unroll 1
    for (int jt = 0; jt < 2; ++jt) {
      if (jt && m <= 16) break;
      const int idx16 = min(jt*16 + r15, m - 1);
      const int lr    = srt[sbase + idx16];

      // B-fragments from fp32 LDS (slot-swizzled b128 reads + pkrtz)
      u32x4 xf[2];
      #pragma unroll
      for (int ks = 0; ks < 2; ++ks) {
        const int s0 = (8*ks +     g) ^ (lr & 7);
        const int s1 = (8*ks + 4 + g) ^ (lr & 7);
        const f32x4 v0 = *(const f32x4*)&pk[lr*DD + s0*4];
        const f32x4 v1 = *(const f32x4*)&pk[lr*DD + s1*4];
        u32x4 t = { pkrtz(v0[0],v0[1]), pkrtz(v0[2],v0[3]),
                    pkrtz(v1[0],v1[1]), pkrtz(v1[2],v1[3]) };
        xf[ks] = t;
      }

      // Layer 1
      f32x4 c[4];
      #pragma unroll
      for (int nt = 0; nt < 4; ++nt) {
        const float4 bv = *(const float4*)(b1 + e*DD + nt*16 + 4*g);
        f32x4 acc = { bv.x, bv.y, bv.z, bv.w };
        acc = mfma16(af[nt*2 + 0], xf[0], acc);
        acc = mfma16(af[nt*2 + 1], xf[1], acc);
        c[nt] = acc;
      }
      const u32x4 h0 = relu_pack(c[0], c[1]);
      const u32x4 h1 = relu_pack(c[2], c[3]);

      // Layer 2
      #pragma unroll
      for (int nt = 0; nt < 4; ++nt) {
        const float4 bv = *(const float4*)(b2 + e*DD + nt*16 + 4*g);
        f32x4 acc = { bv.x, bv.y, bv.z, bv.w };
        acc = mfma16(af[8 + nt*2 + 0], h0, acc);
        acc = mfma16(af[8 + nt*2 + 1], h1, acc);
        c[nt] = acc;
      }
      const u32x4 t0 = relu_pack(c[0], c[1]);
      const u32x4 t1 = relu_pack(c[2], c[3]);

      // Layer 3 + softmax (lanes g==0 hold classes 0..2 of their row)
      f32x4 acc = { b3[e*NDC + 0], b3[e*NDC + 1], b3[e*NDC + 2], 0.f };
      acc = mfma16(af[16], t0, acc);
      acc = mfma16(af[17], t1, acc);

      if (g == 0 && (jt*16 + r15) < m) {
        const int row = base + lr;
        const float l0 = acc[0], l1 = acc[1], l2 = acc[2];
        const float mx  = fmaxf(l0, fmaxf(l1, l2));
        const float p0  = __expf(l0 - mx);
        const float p1  = __expf(l1 - mx);
        const float p2  = __expf(l2 - mx);
        const float inv = 1.0f / (p0 + p1 + p2);
        float* o = out + (size_t)row*3;
        o[0] = l0; o[1] = l1; o[2] = l2;
        float* pr = out + (size_t)B*3 + (size_t)row*3;
        pr[0] = p0*inv; pr[1] = p1*inv; pr[2] = p2*inv;
      }
    }
  }
}

extern "C" void kernel_launch(void* const* d_in, const int* in_sizes, int n_in,
                              void* d_out, int out_size, void* d_ws, size_t ws_size,
                              hipStream_t stream)
{
  const float* X  = (const float*)d_in[0];
  const int*   S  = (const int*)d_in[1];
  const float* W1 = (const float*)d_in[2];
  const float* B1 = (const float*)d_in[3];
  const float* W2 = (const float*)d_in[4];
  const float* B2 = (const float*)d_in[5];
  const float* W3 = (const float*)d_in[6];
  const float* B3 = (const float*)d_in[7];
  float* out = (float*)d_out;
  uint32_t* ws = (uint32_t*)d_ws;

  const int B = in_sizes[0] / DD;   // 262144

  pack_w<<<NE, BLOCK, 0, stream>>>(W1, W2, W3, ws);
  fused<<<B / ROWS, BLOCK, 0, stream>>>(X, S, (const u32x4*)ws,
                                        B1, B2, B3, out, B);
}

// Round 13
// 36.973 us; speedup vs baseline: 1.0170x; 1.0170x over previous
//
#include <hip/hip_runtime.h>
#include <stdint.h>

#define NE    7
#define DD    64
#define NDC   3
#define BLOCK 256
#define ROWS  128       // rows per block; B = 2048 * 128 exactly
#define NFRAG 18        // W^T A-fragments: 8 (L1) + 8 (L2) + 2 (L3)

typedef __fp16   half8 __attribute__((ext_vector_type(8)));
typedef float    f32x4 __attribute__((ext_vector_type(4)));
typedef uint32_t u32x4 __attribute__((ext_vector_type(4)));
typedef uint32_t u32x2 __attribute__((ext_vector_type(2)));
typedef __fp16   h2_t  __attribute__((ext_vector_type(2)));

__device__ __forceinline__ uint32_t pkrtz(float a, float b) {
  h2_t h = __builtin_amdgcn_cvt_pkrtz(a, b);
  return __builtin_bit_cast(uint32_t, h);
}

__device__ __forceinline__ f32x4 mfma16(u32x4 a, u32x4 b, f32x4 c) {
  return __builtin_amdgcn_mfma_f32_16x16x32_f16(
      __builtin_bit_cast(half8, a), __builtin_bit_cast(half8, b), c, 0, 0, 0);
}

__device__ __forceinline__ u32x4 relu_pack(f32x4 lo, f32x4 hi) {
  u32x4 t = { pkrtz(fmaxf(lo[0],0.f), fmaxf(lo[1],0.f)),
              pkrtz(fmaxf(lo[2],0.f), fmaxf(lo[3],0.f)),
              pkrtz(fmaxf(hi[0],0.f), fmaxf(hi[1],0.f)),
              pkrtz(fmaxf(hi[2],0.f), fmaxf(hi[3],0.f)) };
  return t;
}

// ---- pack W^T into A-fragment layout (HW-verified R4), LDS-staged & parallel ----
// grid = 14: block (e, half). half 0: W1 -> frags 0..7 (+ W3 -> 16,17); half 1: W2 -> 8..15.
// lane l: row n = 16*nt + (l&15); dword d, half h: kk = 16*(d>>1)+4*(l>>4)+2*(d&1)+h;
// k = 32*ks + kk; value = W[k][n]  (W row-major [k][n]).
__global__ __launch_bounds__(BLOCK) void pack_w2(
    const float* __restrict__ W1, const float* __restrict__ W2,
    const float* __restrict__ W3, uint32_t* __restrict__ ws) {
  __shared__ float wt[DD*DD];   // 16 KB
  const int blk = blockIdx.x;
  const int e = blk >> 1, half = blk & 1;
  const float* Wsrc = (half ? W2 : W1) + (size_t)e*DD*DD;

  const float4* s4 = (const float4*)Wsrc;
  float4* d4 = (float4*)wt;
  #pragma unroll
  for (int i = 0; i < DD*DD/4/BLOCK; ++i)
    d4[i*BLOCK + threadIdx.x] = s4[i*BLOCK + threadIdx.x];   // coalesced 16-KB stage
  __syncthreads();

  for (int idx = threadIdx.x; idx < 8*64; idx += BLOCK) {
    const int fl = idx >> 6, l = idx & 63;
    const int nt = fl >> 1, ks = fl & 1;
    const int n  = nt*16 + (l & 15), g = l >> 4;
    uint32_t dst[4];
    #pragma unroll
    for (int d = 0; d < 4; ++d) {
      float v[2];
      #pragma unroll
      for (int h = 0; h < 2; ++h) {
        const int kk = 16*(d>>1) + 4*g + 2*(d&1) + h;
        v[h] = wt[(32*ks + kk)*DD + n];
      }
      dst[d] = pkrtz(v[0], v[1]);
    }
    uint32_t* p = ws + ((size_t)(e*NFRAG + half*8 + fl)*64 + l)*4;
    p[0]=dst[0]; p[1]=dst[1]; p[2]=dst[2]; p[3]=dst[3];
  }

  if (half == 0) {   // W3 -> frags 16,17 (tiny)
    const float* Wl2 = W3 + (size_t)e*DD*NDC;
    for (int idx = threadIdx.x; idx < 2*64; idx += BLOCK) {
      const int ks = idx >> 6, l = idx & 63;
      const int n  = l & 15, g = l >> 4;
      uint32_t dst[4];
      #pragma unroll
      for (int d = 0; d < 4; ++d) {
        float v[2];
        #pragma unroll
        for (int h = 0; h < 2; ++h) {
          const int kk = 16*(d>>1) + 4*g + 2*(d&1) + h;
          const int k  = 32*ks + kk;
          v[h] = (n < NDC) ? Wl2[k*NDC + n] : 0.0f;
        }
        dst[d] = pkrtz(v[0], v[1]);
      }
      uint32_t* p = ws + ((size_t)(e*NFRAG + 16 + ks)*64 + l)*4;
      p[0]=dst[0]; p[1]=dst[1]; p[2]=dst[2]; p[3]=dst[3];
    }
  }
}

// ---- fused: coalesced X->fp16 LDS -> in-block sort -> grouped MFMA -> coalesced out ----
__global__ __launch_bounds__(BLOCK, 4) void fused(
    const float* __restrict__ X, const int* __restrict__ S,
    const u32x4* __restrict__ wf,
    const float* __restrict__ b1, const float* __restrict__ b2,
    const float* __restrict__ b3,
    float* __restrict__ out, int B)
{
  __shared__ uint32_t pk[ROWS*32];     // 16 KB packed fp16 X, slot-swizzled
  __shared__ float    outbuf[ROWS*6];  // 3 KB  (l0,l1,l2,p0,p1,p2 per row)
  __shared__ uint16_t srt[ROWS];
  __shared__ int wcnt[2][NE];
  __shared__ int woff[2][NE];
  __shared__ int cnt[NE];

  const int tid  = threadIdx.x;
  const int wv   = tid >> 6, lane = tid & 63;
  const int r15  = lane & 15, g = lane >> 4;
  const int base = blockIdx.x * ROWS;

  // ---- A1: route ballots (waves 0-1 own the 128 rows) ----
  int e_i = 0, myprefix = 0;
  if (wv < 2) {
    e_i = S[base + tid];
    unsigned long long mk[NE];
    #pragma unroll
    for (int e = 0; e < NE; ++e) mk[e] = __ballot(e_i == e);
    #pragma unroll
    for (int e = 0; e < NE; ++e)
      if (e_i == e) myprefix = __popcll(mk[e] & ((1ull << lane) - 1ull));
    if (lane < NE) wcnt[wv][lane] = __popcll(mk[lane]);
  }
  __syncthreads();

  // ---- A2 (tid0 serial scan) overlapped with B (X -> LDS fp16 pack, 1-KB streams) ----
  if (tid == 0) {
    int acc = 0;
    for (int e = 0; e < NE; ++e) {
      const int s0 = acc;
      for (int w = 0; w < 2; ++w) { woff[w][e] = acc; acc += wcnt[w][e]; }
      cnt[e] = acc - s0;
    }
  }
  {
    const float4* Xb = (const float4*)(X + (size_t)base * DD);
    const int q     = lane & 15;
    const int rsub  = lane >> 4;
    const int ksq   = q >> 3, gq = q & 3, hq = (q >> 2) & 1;
    const int slotq = 4*ksq + gq;
    #pragma unroll
    for (int it = 0; it < 8; ++it) {
      const int r = wv*32 + it*4 + rsub;
      const float4 v = Xb[r*16 + q];             // 1-KB contiguous per instr
      u32x2 w2 = { pkrtz(v.x, v.y), pkrtz(v.z, v.w) };
      *(u32x2*)&pk[r*32 + ((slotq ^ (r & 7)) << 2) + hq*2] = w2;
    }
  }
  __syncthreads();

  // ---- A3: scatter sorted list ----
  if (tid < ROWS) srt[woff[wv][e_i] + myprefix] = (uint16_t)tid;
  __syncthreads();

  // ---- C: grouped MFMA passes; af file split in two 8-frag stages (VGPR<=128) ----
  int pst[NE + 1];
  {
    int tp = 0;
    #pragma unroll
    for (int e = 0; e < NE; ++e) { pst[e] = tp; tp += (cnt[e] + 31) >> 5; }
    pst[NE] = tp;
  }

  for (int p = wv; p < pst[NE]; p += 4) {
    int e = 0;
    #pragma unroll
    for (int q2 = 1; q2 < NE; ++q2) if (p >= pst[q2]) e = q2;
    const int ch    = p - pst[e];
    const int m     = min(32, cnt[e] - ch*32);
    const int sbase = woff[0][e] + ch*32;
    const int njt   = (m > 16) ? 2 : 1;

    const u32x4* wse = wf + (size_t)e*NFRAG*64;

    // stage 1: L1 fragments (issued before LDS reads)
    u32x4 afA[8];
    #pragma unroll
    for (int f = 0; f < 8; ++f) afA[f] = wse[f*64 + lane];

    int lr[2] = {0, 0};
    u32x4 xf[2][2];
    #pragma unroll
    for (int jt = 0; jt < 2; ++jt) {
      if (jt >= njt) break;
      const int idx16 = min(jt*16 + r15, m - 1);
      lr[jt] = srt[sbase + idx16];
      xf[jt][0] = *(const u32x4*)&pk[lr[jt]*32 + (((    g) ^ (lr[jt] & 7)) << 2)];
      xf[jt][1] = *(const u32x4*)&pk[lr[jt]*32 + (((4 + g) ^ (lr[jt] & 7)) << 2)];
    }

    // Layer 1
    u32x4 h[2][2];
    #pragma unroll
    for (int jt = 0; jt < 2; ++jt) {
      if (jt >= njt) break;
      f32x4 c[4];
      #pragma unroll
      for (int nt = 0; nt < 4; ++nt) {
        const float4 bv = *(const float4*)(b1 + e*DD + nt*16 + 4*g);
        f32x4 acc = { bv.x, bv.y, bv.z, bv.w };
        acc = mfma16(afA[nt*2 + 0], xf[jt][0], acc);
        acc = mfma16(afA[nt*2 + 1], xf[jt][1], acc);
        c[nt] = acc;
      }
      h[jt][0] = relu_pack(c[0], c[1]);
      h[jt][1] = relu_pack(c[2], c[3]);
    }

    // stage 2: L2 fragments (overwrite afA)
    #pragma unroll
    for (int f = 0; f < 8; ++f) afA[f] = wse[(8 + f)*64 + lane];

    u32x4 t[2][2];
    #pragma unroll
    for (int jt = 0; jt < 2; ++jt) {
      if (jt >= njt) break;
      f32x4 c[4];
      #pragma unroll
      for (int nt = 0; nt < 4; ++nt) {
        const float4 bv = *(const float4*)(b2 + e*DD + nt*16 + 4*g);
        f32x4 acc = { bv.x, bv.y, bv.z, bv.w };
        acc = mfma16(afA[nt*2 + 0], h[jt][0], acc);
        acc = mfma16(afA[nt*2 + 1], h[jt][1], acc);
        c[nt] = acc;
      }
      t[jt][0] = relu_pack(c[0], c[1]);
      t[jt][1] = relu_pack(c[2], c[3]);
    }

    // Layer 3 + softmax -> outbuf
    const u32x4 a30 = wse[16*64 + lane];
    const u32x4 a31 = wse[17*64 + lane];
    #pragma unroll
    for (int jt = 0; jt < 2; ++jt) {
      if (jt >= njt) break;
      f32x4 acc = { b3[e*NDC + 0], b3[e*NDC + 1], b3[e*NDC + 2], 0.f };
      acc = mfma16(a30, t[jt][0], acc);
      acc = mfma16(a31, t[jt][1], acc);
      if (g == 0 && (jt*16 + r15) < m) {
        const float l0 = acc[0], l1 = acc[1], l2 = acc[2];
        const float mx  = fmaxf(l0, fmaxf(l1, l2));
        const float p0  = __expf(l0 - mx);
        const float p1  = __expf(l1 - mx);
        const float p2  = __expf(l2 - mx);
        const float inv = 1.0f / (p0 + p1 + p2);
        float* ob = outbuf + lr[jt]*6;
        ob[0] = l0;      ob[1] = l1;      ob[2] = l2;
        ob[3] = p0*inv;  ob[4] = p1*inv;  ob[5] = p2*inv;
      }
    }
  }
  __syncthreads();

  // ---- D: coalesced output (two contiguous streams; 384 elems > 256 threads -> loop) ----
  for (int i = tid; i < ROWS*3; i += BLOCK) {
    const int r = i/3, c2 = i - r*3;
    out[(size_t)base*3 + i]                = outbuf[r*6 + c2];
    out[(size_t)B*3 + (size_t)base*3 + i]  = outbuf[r*6 + 3 + c2];
  }
}

extern "C" void kernel_launch(void* const* d_in, const int* in_sizes, int n_in,
                              void* d_out, int out_size, void* d_ws, size_t ws_size,
                              hipStream_t stream)
{
  const float* X  = (const float*)d_in[0];
  const int*   S  = (const int*)d_in[1];
  const float* W1 = (const float*)d_in[2];
  const float* B1 = (const float*)d_in[3];
  const float* W2 = (const float*)d_in[4];
  const float* B2 = (const float*)d_in[5];
  const float* W3 = (const float*)d_in[6];
  const float* B3 = (const float*)d_in[7];
  float* out = (float*)d_out;
  uint32_t* ws = (uint32_t*)d_ws;

  const int B = in_sizes[0] / DD;   // 262144

  pack_w2<<<NE*2, BLOCK, 0, stream>>>(W1, W2, W3, ws);
  fused<<<B / ROWS, BLOCK, 0, stream>>>(X, S, (const u32x4*)ws,
                                        B1, B2, B3, out, B);
}